// Round 6
// baseline (258.104 us; speedup 1.0000x reference)
//
#include <hip/hip_runtime.h>
#include <hip/hip_bf16.h>

#define BATCH 4096
#define HIDDEN 512
#define BN_EPS 1e-5f

typedef unsigned int u32;
typedef unsigned short u16;
typedef float f32x4 __attribute__((ext_vector_type(4)));   // clang-native vec for nontemporal builtin

__device__ __forceinline__ float bf2f(u32 lo) { return __uint_as_float(lo << 16); }
__device__ __forceinline__ u32 f2bf(float f) {
    u32 u = __float_as_uint(f);
    return (u + 0x7FFFu + ((u >> 16) & 1u)) >> 16;          // round-to-nearest-even
}

// ---------------------------------------------------------------------------
// K0: detect float-input dtype (bf16 vs fp32) from emb bit patterns.
__global__ void k_detect(const u32* __restrict__ emb_w, int* __restrict__ flag) {
    const int lane = threadIdx.x;
    u32 v = emb_w[(size_t)lane * 400009u + 17u];
    float a = fabsf(bf2f(v & 0xffffu));
    bool bf_like = (a > 0.0009765625f) && (a < 16.0f);
    unsigned long long m = __ballot(bf_like);
    if (lane == 0) flag[0] = (__popcll(m) >= 48) ? 1 : 0;
}

// ---------------------------------------------------------------------------
// K0b: fp32 emb -> bf16 table in workspace (no-op if inputs already bf16).
// nt loads: don't pollute caches with the 205 MB one-shot fp32 stream.
__global__ __launch_bounds__(256) void k_convert(const f32x4* __restrict__ src,
                                                 uint2* __restrict__ dst,
                                                 const int* __restrict__ flag, int n4) {
    if (flag[0]) return;
    int i = blockIdx.x * blockDim.x + threadIdx.x;
    const int stride = gridDim.x * blockDim.x;
    for (; i < n4; i += stride) {
        f32x4 v = __builtin_nontemporal_load(src + i);
        uint2 o;
        o.x = f2bf(v.x) | (f2bf(v.y) << 16);
        o.y = f2bf(v.z) | (f2bf(v.w) << 16);
        dst[i] = o;
    }
}

// ---------------------------------------------------------------------------
// K1: ragged mean-pool. One block (4 waves) per segment; each wave takes a
// contiguous quarter of the segment's tokens; unroll-8 => 8 independent 16B
// row-gathers in flight per lane (MLP test vs round-5's unroll-4).
// Output pooled is written as BF16 (halves pooled traffic; k_gemm decodes).
__global__ __launch_bounds__(256) void k_pool(const int* __restrict__ tokens,
                                              const int* __restrict__ seg,
                                              const void* __restrict__ emb,
                                              const u16* __restrict__ table,
                                              const int* __restrict__ flag,
                                              int use_table,
                                              u32* __restrict__ pooled_bf, int T) {
    const int b = blockIdx.x;
    int lo = 0, hi = T;
    while (lo < hi) { int m = (lo + hi) >> 1; if (seg[m] < b) lo = m + 1; else hi = m; }
    const int start = lo;
    hi = T;
    while (lo < hi) { int m = (lo + hi) >> 1; if (seg[m] < b + 1) lo = m + 1; else hi = m; }
    const int end = lo;
    const int cnt = end - start;

    const int wv = threadIdx.x >> 6;
    const int lane = threadIdx.x & 63;
    const int chunk = (cnt + 3) >> 2;
    const int ts = start + wv * chunk;
    const int te = min(ts + chunk, end);

    float acc[8] = {0.f,0.f,0.f,0.f,0.f,0.f,0.f,0.f};
    const int bf = flag[0];

    if (bf || use_table) {
        const u16* src = bf ? (const u16*)emb : table;
        int t = ts;
        for (; t + 8 <= te; t += 8) {
            uint4 v0 = *(const uint4*)(src + (size_t)tokens[t]     * HIDDEN + lane * 8);
            uint4 v1 = *(const uint4*)(src + (size_t)tokens[t + 1] * HIDDEN + lane * 8);
            uint4 v2 = *(const uint4*)(src + (size_t)tokens[t + 2] * HIDDEN + lane * 8);
            uint4 v3 = *(const uint4*)(src + (size_t)tokens[t + 3] * HIDDEN + lane * 8);
            uint4 v4 = *(const uint4*)(src + (size_t)tokens[t + 4] * HIDDEN + lane * 8);
            uint4 v5 = *(const uint4*)(src + (size_t)tokens[t + 5] * HIDDEN + lane * 8);
            uint4 v6 = *(const uint4*)(src + (size_t)tokens[t + 6] * HIDDEN + lane * 8);
            uint4 v7 = *(const uint4*)(src + (size_t)tokens[t + 7] * HIDDEN + lane * 8);
#define ACC_BF(v) \
            acc[0] += bf2f(v.x & 0xffffu); acc[1] += bf2f(v.x >> 16); \
            acc[2] += bf2f(v.y & 0xffffu); acc[3] += bf2f(v.y >> 16); \
            acc[4] += bf2f(v.z & 0xffffu); acc[5] += bf2f(v.z >> 16); \
            acc[6] += bf2f(v.w & 0xffffu); acc[7] += bf2f(v.w >> 16);
            ACC_BF(v0); ACC_BF(v1); ACC_BF(v2); ACC_BF(v3);
            ACC_BF(v4); ACC_BF(v5); ACC_BF(v6); ACC_BF(v7);
        }
        for (; t < te; ++t) {
            uint4 v = *(const uint4*)(src + (size_t)tokens[t] * HIDDEN + lane * 8);
            ACC_BF(v);
#undef ACC_BF
        }
    } else {
        const float* e = (const float*)emb;
        for (int t = ts; t < te; ++t) {
            const float* p = e + (size_t)tokens[t] * HIDDEN + lane * 8;
            float4 a = *(const float4*)p, b2_ = *(const float4*)(p + 4);
            acc[0] += a.x; acc[1] += a.y; acc[2] += a.z; acc[3] += a.w;
            acc[4] += b2_.x; acc[5] += b2_.y; acc[6] += b2_.z; acc[7] += b2_.w;
        }
    }

    // cross-wave combine: red[w][k][lane] layout -> conflict-free (lane stride 1)
    __shared__ float red[4][8][64];
    if (wv > 0) {
#pragma unroll
        for (int k = 0; k < 8; ++k) red[wv][k][lane] = acc[k];
    }
    __syncthreads();
    if (wv == 0) {
#pragma unroll
        for (int k = 0; k < 8; ++k)
            acc[k] += red[1][k][lane] + red[2][k][lane] + red[3][k][lane];
        const float inv = (cnt > 0) ? (1.0f / (float)cnt) : 1.0f;
        // pack 8 fp32 -> 8 bf16 (4 words)
        uint4 o;
        o.x = f2bf(acc[0] * inv) | (f2bf(acc[1] * inv) << 16);
        o.y = f2bf(acc[2] * inv) | (f2bf(acc[3] * inv) << 16);
        o.z = f2bf(acc[4] * inv) | (f2bf(acc[5] * inv) << 16);
        o.w = f2bf(acc[6] * inv) | (f2bf(acc[7] * inv) << 16);
        *(uint4*)(pooled_bf + (size_t)b * (HIDDEN / 2) + lane * 4) = o;
    }
}

// ---------------------------------------------------------------------------
// K2: h = pooled @ W_h + b_h (fp32 accumulate on VALU; A is bf16-packed).
// Block = 256 threads: 8 rows x 512 cols; A tile decoded bf16->f32 into LDS.
__global__ __launch_bounds__(256) void k_gemm(const u32* __restrict__ pooled_bf,
                                              const void* __restrict__ W,
                                              const void* __restrict__ bias,
                                              const int* __restrict__ flag,
                                              float* __restrict__ h) {
    __shared__ float sp[8 * HIDDEN];
    const int tid = threadIdx.x;
    const int rb = blockIdx.x;
    const u32* prow = pooled_bf + (size_t)rb * 8 * (HIDDEN / 2);
    for (int i = tid; i < 8 * HIDDEN / 2; i += 256) {        // 2048 words
        u32 w = prow[i];
        sp[i * 2]     = bf2f(w & 0xffffu);
        sp[i * 2 + 1] = bf2f(w >> 16);
    }
    __syncthreads();

    const int j4 = tid & 127;
    const int r0 = (tid >> 7) * 4;
    float4 acc[4] = {};

    if (flag[0]) {
        const u32* W2 = (const u32*)W;
#pragma unroll 4
        for (int c = 0; c < HIDDEN; ++c) {
            uint2 wu = *(const uint2*)(W2 + (size_t)c * (HIDDEN / 2) + j4 * 2);
            float w0 = bf2f(wu.x & 0xffffu), w1 = bf2f(wu.x >> 16);
            float w2 = bf2f(wu.y & 0xffffu), w3 = bf2f(wu.y >> 16);
#pragma unroll
            for (int r = 0; r < 4; ++r) {
                float p = sp[(r0 + r) * HIDDEN + c];
                acc[r].x = fmaf(p, w0, acc[r].x);
                acc[r].y = fmaf(p, w1, acc[r].y);
                acc[r].z = fmaf(p, w2, acc[r].z);
                acc[r].w = fmaf(p, w3, acc[r].w);
            }
        }
    } else {
        const float4* W4 = (const float4*)W;
#pragma unroll 4
        for (int c = 0; c < HIDDEN; ++c) {
            float4 w = W4[(size_t)c * 128 + j4];
#pragma unroll
            for (int r = 0; r < 4; ++r) {
                float p = sp[(r0 + r) * HIDDEN + c];
                acc[r].x = fmaf(p, w.x, acc[r].x);
                acc[r].y = fmaf(p, w.y, acc[r].y);
                acc[r].z = fmaf(p, w.z, acc[r].z);
                acc[r].w = fmaf(p, w.w, acc[r].w);
            }
        }
    }

    float bv[4];
    if (flag[0]) {
        uint2 bu = *(const uint2*)((const u32*)bias + j4 * 2);
        bv[0] = bf2f(bu.x & 0xffffu); bv[1] = bf2f(bu.x >> 16);
        bv[2] = bf2f(bu.y & 0xffffu); bv[3] = bf2f(bu.y >> 16);
    } else {
        float4 b4 = ((const float4*)bias)[j4];
        bv[0] = b4.x; bv[1] = b4.y; bv[2] = b4.z; bv[3] = b4.w;
    }
#pragma unroll
    for (int r = 0; r < 4; ++r) {
        float4 o = make_float4(acc[r].x + bv[0], acc[r].y + bv[1],
                               acc[r].z + bv[2], acc[r].w + bv[3]);
        ((float4*)(h + (size_t)(rb * 8 + r0 + r) * HIDDEN))[j4] = o;
    }
}

// ---------------------------------------------------------------------------
// K3: per-column sum / sum-of-squares over the batch (BN batch stats).
__global__ __launch_bounds__(512) void k_stats(const float* __restrict__ h,
                                               float* __restrict__ sums,
                                               float* __restrict__ sumsq) {
    const int tid = threadIdx.x;
    const int r0 = blockIdx.x * 64;
    float s = 0.f, q = 0.f;
    for (int r = r0; r < r0 + 64; ++r) {
        float v = h[(size_t)r * HIDDEN + tid];
        s += v;
        q = fmaf(v, v, q);
    }
    atomicAdd(&sums[tid], s);
    atomicAdd(&sumsq[tid], q);
}

// ---------------------------------------------------------------------------
// K4: BN(batch stats) + ReLU + dot W_o + b_o -> logits; per-row BCE term.
__global__ __launch_bounds__(256) void k_out(const float* __restrict__ h,
                                             const float* __restrict__ sums,
                                             const float* __restrict__ sumsq,
                                             const void* __restrict__ gamma,
                                             const void* __restrict__ beta,
                                             const void* __restrict__ W_o,
                                             const void* __restrict__ b_o,
                                             const void* __restrict__ tvec,
                                             const int* __restrict__ flag,
                                             void* __restrict__ out,
                                             float* __restrict__ loss_acc) {
    const int lane = threadIdx.x & 63;
    const int wave = threadIdx.x >> 6;
    const int row  = blockIdx.x * 4 + wave;
    const float invN = 1.0f / (float)BATCH;
    const int bf = flag[0];
    const int c0 = lane * 8;

    float g[8], bt[8], wo[8];
    if (bf) {
        uint4 gu = *(const uint4*)((const u32*)gamma + lane * 4);
        uint4 bu = *(const uint4*)((const u32*)beta  + lane * 4);
        uint4 wu = *(const uint4*)((const u32*)W_o   + lane * 4);
        g[0]=bf2f(gu.x&0xffffu); g[1]=bf2f(gu.x>>16); g[2]=bf2f(gu.y&0xffffu); g[3]=bf2f(gu.y>>16);
        g[4]=bf2f(gu.z&0xffffu); g[5]=bf2f(gu.z>>16); g[6]=bf2f(gu.w&0xffffu); g[7]=bf2f(gu.w>>16);
        bt[0]=bf2f(bu.x&0xffffu); bt[1]=bf2f(bu.x>>16); bt[2]=bf2f(bu.y&0xffffu); bt[3]=bf2f(bu.y>>16);
        bt[4]=bf2f(bu.z&0xffffu); bt[5]=bf2f(bu.z>>16); bt[6]=bf2f(bu.w&0xffffu); bt[7]=bf2f(bu.w>>16);
        wo[0]=bf2f(wu.x&0xffffu); wo[1]=bf2f(wu.x>>16); wo[2]=bf2f(wu.y&0xffffu); wo[3]=bf2f(wu.y>>16);
        wo[4]=bf2f(wu.z&0xffffu); wo[5]=bf2f(wu.z>>16); wo[6]=bf2f(wu.w&0xffffu); wo[7]=bf2f(wu.w>>16);
    } else {
        float4 a, b2;
        a = *(const float4*)((const float*)gamma + c0); b2 = *(const float4*)((const float*)gamma + c0 + 4);
        g[0]=a.x; g[1]=a.y; g[2]=a.z; g[3]=a.w; g[4]=b2.x; g[5]=b2.y; g[6]=b2.z; g[7]=b2.w;
        a = *(const float4*)((const float*)beta + c0);  b2 = *(const float4*)((const float*)beta + c0 + 4);
        bt[0]=a.x; bt[1]=a.y; bt[2]=a.z; bt[3]=a.w; bt[4]=b2.x; bt[5]=b2.y; bt[6]=b2.z; bt[7]=b2.w;
        a = *(const float4*)((const float*)W_o + c0);   b2 = *(const float4*)((const float*)W_o + c0 + 4);
        wo[0]=a.x; wo[1]=a.y; wo[2]=a.z; wo[3]=a.w; wo[4]=b2.x; wo[5]=b2.y; wo[6]=b2.z; wo[7]=b2.w;
    }

    float hv[8], sm[8], sq[8];
    {
        const float* hp = h + (size_t)row * HIDDEN + c0;
        float4 a = *(const float4*)hp, b2 = *(const float4*)(hp + 4);
        hv[0]=a.x; hv[1]=a.y; hv[2]=a.z; hv[3]=a.w; hv[4]=b2.x; hv[5]=b2.y; hv[6]=b2.z; hv[7]=b2.w;
        a = *(const float4*)(sums + c0);  b2 = *(const float4*)(sums + c0 + 4);
        sm[0]=a.x; sm[1]=a.y; sm[2]=a.z; sm[3]=a.w; sm[4]=b2.x; sm[5]=b2.y; sm[6]=b2.z; sm[7]=b2.w;
        a = *(const float4*)(sumsq + c0); b2 = *(const float4*)(sumsq + c0 + 4);
        sq[0]=a.x; sq[1]=a.y; sq[2]=a.z; sq[3]=a.w; sq[4]=b2.x; sq[5]=b2.y; sq[6]=b2.z; sq[7]=b2.w;
    }

    float sum = 0.f;
#pragma unroll
    for (int k = 0; k < 8; ++k) {
        float mu  = sm[k] * invN;
        float var = sq[k] * invN - mu * mu;
        float xn  = (hv[k] - mu) * rsqrtf(var + BN_EPS);
        float y   = fmaf(g[k], xn, bt[k]);
        y = fmaxf(y, 0.f);
        sum = fmaf(y, wo[k], sum);
    }
#pragma unroll
    for (int o = 32; o > 0; o >>= 1) sum += __shfl_xor(sum, o);

    __shared__ float ls[4];
    if (lane == 0) {
        float bo = bf ? bf2f(((const u16*)b_o)[0]) : ((const float*)b_o)[0];
        float x = sum + bo;
        if (bf) ((u16*)out)[1 + row] = (u16)f2bf(x);
        else    ((float*)out)[1 + row] = x;
        float t = bf ? bf2f(((const u16*)tvec)[row]) : ((const float*)tvec)[row];
        float sp = fmaxf(x, 0.f) + log1pf(expf(-fabsf(x)));
        ls[wave] = sp - t * x;
    }
    __syncthreads();
    if (threadIdx.x == 0)
        atomicAdd(loss_acc, ls[0] + ls[1] + ls[2] + ls[3]);
}

// ---------------------------------------------------------------------------
// K5: finalize mean loss.
__global__ void k_fin(const float* __restrict__ loss_acc,
                      const int* __restrict__ flag, void* __restrict__ out) {
    if (threadIdx.x == 0) {
        float v = loss_acc[0] * (1.0f / (float)BATCH);
        if (flag[0]) ((u16*)out)[0] = (u16)f2bf(v);
        else         ((float*)out)[0] = v;
    }
}

// ---------------------------------------------------------------------------
extern "C" void kernel_launch(void* const* d_in, const int* in_sizes, int n_in,
                              void* d_out, int out_size, void* d_ws, size_t ws_size,
                              hipStream_t stream) {
    const int*  tokens = (const int*)d_in[0];
    const int*  seg    = (const int*)d_in[1];
    const void* tvec   = d_in[2];
    const void* emb    = d_in[3];
    const void* W_h    = d_in[4];
    const void* b_h    = d_in[5];
    const void* gamma  = d_in[6];
    const void* beta   = d_in[7];
    const void* W_o    = d_in[8];
    const void* b_o    = d_in[9];
    const int T = in_sizes[0];
    const int vocab = in_sizes[3] / HIDDEN;

    char* ws = (char*)d_ws;
    u32*   pooled_bf = (u32*)ws;                               // 4 MB (bf16-packed)
    float* h         = (float*)(ws + (size_t)8 * 1024 * 1024); // 8 MB
    float* sums      = (float*)(ws + (size_t)16 * 1024 * 1024);
    float* sumsq     = sums + HIDDEN;
    float* loss_acc  = sums + 2 * HIDDEN;
    int*   flag      = (int*)(loss_acc + 1);
    const size_t TABLE_OFF = (size_t)17 * 1024 * 1024;
    const size_t TABLE_BYTES = (size_t)vocab * HIDDEN * 2;
    u16* table = (u16*)(ws + TABLE_OFF);
    const int use_table = (ws_size >= TABLE_OFF + TABLE_BYTES) ? 1 : 0;

    (void)hipMemsetAsync(sums, 0, (2 * HIDDEN + 1) * sizeof(float), stream);

    k_detect<<<1, 64, 0, stream>>>((const u32*)emb, flag);
    if (use_table) {
        const int n4 = vocab * HIDDEN / 4;
        k_convert<<<2048, 256, 0, stream>>>((const f32x4*)emb, (uint2*)table, flag, n4);
    }
    k_pool  <<<BATCH,     256, 0, stream>>>(tokens, seg, emb, table, flag, use_table, pooled_bf, T);
    k_gemm  <<<BATCH / 8, 256, 0, stream>>>(pooled_bf, W_h, b_h, flag, h);
    k_stats <<<BATCH / 64,512, 0, stream>>>(h, sums, sumsq);
    k_out   <<<BATCH / 4, 256, 0, stream>>>(h, sums, sumsq, gamma, beta,
                                            W_o, b_o, tvec, flag, d_out, loss_acc);
    k_fin   <<<1, 64, 0, stream>>>(loss_acc, flag, d_out);
}

// Round 7
// 241.981 us; speedup vs baseline: 1.0666x; 1.0666x over previous
//
#include <hip/hip_runtime.h>
#include <hip/hip_bf16.h>

#define BATCH 4096
#define HIDDEN 512
#define BN_EPS 1e-5f

typedef unsigned int u32;
typedef unsigned short u16;
typedef float f32x4 __attribute__((ext_vector_type(4)));
typedef __bf16 bf16x8 __attribute__((ext_vector_type(8)));

__device__ __forceinline__ float bf2f(u32 lo) { return __uint_as_float(lo << 16); }
__device__ __forceinline__ u32 f2bf(float f) {
    u32 u = __float_as_uint(f);
    return (u + 0x7FFFu + ((u >> 16) & 1u)) >> 16;          // round-to-nearest-even
}

// ---------------------------------------------------------------------------
// K0: detect float-input dtype (bf16 vs fp32) from emb bit patterns.
__global__ void k_detect(const u32* __restrict__ emb_w, int* __restrict__ flag) {
    const int lane = threadIdx.x;
    u32 v = emb_w[(size_t)lane * 400009u + 17u];
    float a = fabsf(bf2f(v & 0xffffu));
    bool bf_like = (a > 0.0009765625f) && (a < 16.0f);
    unsigned long long m = __ballot(bf_like);
    if (lane == 0) flag[0] = (__popcll(m) >= 48) ? 1 : 0;
}

// ---------------------------------------------------------------------------
// K0b: fp32 emb -> bf16 table in workspace (no-op if inputs already bf16).
__global__ __launch_bounds__(256) void k_convert(const f32x4* __restrict__ src,
                                                 uint2* __restrict__ dst,
                                                 const int* __restrict__ flag, int n4) {
    if (flag[0]) return;
    int i = blockIdx.x * blockDim.x + threadIdx.x;
    const int stride = gridDim.x * blockDim.x;
    for (; i < n4; i += stride) {
        f32x4 v = __builtin_nontemporal_load(src + i);
        uint2 o;
        o.x = f2bf(v.x) | (f2bf(v.y) << 16);
        o.y = f2bf(v.z) | (f2bf(v.w) << 16);
        dst[i] = o;
    }
}

// ---------------------------------------------------------------------------
// K1: ragged mean-pool. One block (4 waves) per segment; each wave a
// contiguous quarter of the segment's tokens; unroll-4 (round-5 optimum:
// VGPR 28, 77% occupancy — unroll-8 cost occupancy, no BW gain).
// At the delivered-BW roofline (~6.4 TB/s). Output packed bf16.
__global__ __launch_bounds__(256) void k_pool(const int* __restrict__ tokens,
                                              const int* __restrict__ seg,
                                              const void* __restrict__ emb,
                                              const u16* __restrict__ table,
                                              const int* __restrict__ flag,
                                              int use_table,
                                              u32* __restrict__ pooled_bf, int T) {
    const int b = blockIdx.x;
    int lo = 0, hi = T;
    while (lo < hi) { int m = (lo + hi) >> 1; if (seg[m] < b) lo = m + 1; else hi = m; }
    const int start = lo;
    hi = T;
    while (lo < hi) { int m = (lo + hi) >> 1; if (seg[m] < b + 1) lo = m + 1; else hi = m; }
    const int end = lo;
    const int cnt = end - start;

    const int wv = threadIdx.x >> 6;
    const int lane = threadIdx.x & 63;
    const int chunk = (cnt + 3) >> 2;
    const int ts = start + wv * chunk;
    const int te = min(ts + chunk, end);

    float acc[8] = {0.f,0.f,0.f,0.f,0.f,0.f,0.f,0.f};
    const int bf = flag[0];

    if (bf || use_table) {
        const u16* src = bf ? (const u16*)emb : table;
        int t = ts;
        for (; t + 4 <= te; t += 4) {
            uint4 v0 = *(const uint4*)(src + (size_t)tokens[t]     * HIDDEN + lane * 8);
            uint4 v1 = *(const uint4*)(src + (size_t)tokens[t + 1] * HIDDEN + lane * 8);
            uint4 v2 = *(const uint4*)(src + (size_t)tokens[t + 2] * HIDDEN + lane * 8);
            uint4 v3 = *(const uint4*)(src + (size_t)tokens[t + 3] * HIDDEN + lane * 8);
#define ACC_BF(v) \
            acc[0] += bf2f(v.x & 0xffffu); acc[1] += bf2f(v.x >> 16); \
            acc[2] += bf2f(v.y & 0xffffu); acc[3] += bf2f(v.y >> 16); \
            acc[4] += bf2f(v.z & 0xffffu); acc[5] += bf2f(v.z >> 16); \
            acc[6] += bf2f(v.w & 0xffffu); acc[7] += bf2f(v.w >> 16);
            ACC_BF(v0); ACC_BF(v1); ACC_BF(v2); ACC_BF(v3);
        }
        for (; t < te; ++t) {
            uint4 v = *(const uint4*)(src + (size_t)tokens[t] * HIDDEN + lane * 8);
            ACC_BF(v);
#undef ACC_BF
        }
    } else {
        const float* e = (const float*)emb;
        for (int t = ts; t < te; ++t) {
            const float* p = e + (size_t)tokens[t] * HIDDEN + lane * 8;
            float4 a = *(const float4*)p, b2_ = *(const float4*)(p + 4);
            acc[0] += a.x; acc[1] += a.y; acc[2] += a.z; acc[3] += a.w;
            acc[4] += b2_.x; acc[5] += b2_.y; acc[6] += b2_.z; acc[7] += b2_.w;
        }
    }

    __shared__ float red[4][8][64];
    if (wv > 0) {
#pragma unroll
        for (int k = 0; k < 8; ++k) red[wv][k][lane] = acc[k];
    }
    __syncthreads();
    if (wv == 0) {
#pragma unroll
        for (int k = 0; k < 8; ++k)
            acc[k] += red[1][k][lane] + red[2][k][lane] + red[3][k][lane];
        const float inv = (cnt > 0) ? (1.0f / (float)cnt) : 1.0f;
        uint4 o;
        o.x = f2bf(acc[0] * inv) | (f2bf(acc[1] * inv) << 16);
        o.y = f2bf(acc[2] * inv) | (f2bf(acc[3] * inv) << 16);
        o.z = f2bf(acc[4] * inv) | (f2bf(acc[5] * inv) << 16);
        o.w = f2bf(acc[6] * inv) | (f2bf(acc[7] * inv) << 16);
        *(uint4*)(pooled_bf + (size_t)b * (HIDDEN / 2) + lane * 4) = o;
    }
}

// ---------------------------------------------------------------------------
// K2: h = pooled @ W_h + b_h via MFMA 16x16x32 bf16.
// Block = 256 thr (4 waves) computes 64 rows x 64 cols; wave w owns rows
// [w*16,w*16+16). Layouts (m89/m91-verified): A row=lane&15,k=8*(lane>>4)+i;
// B col=lane&15, same k; C col=lane&15, row=(lane>>4)*4+reg.
// W read direct from global (L2-hot, 64 MB total vs old 512 MB).
__global__ __launch_bounds__(256) void k_gemm(const u32* __restrict__ pooled_bf,
                                              const void* __restrict__ W,
                                              const void* __restrict__ bias,
                                              const int* __restrict__ flag,
                                              float* __restrict__ h) {
    const int tid  = threadIdx.x;
    const int wv   = tid >> 6;
    const int lane = tid & 63;
    const int l15  = lane & 15;
    const int hi   = lane >> 4;                 // 0..3
    const int rb   = (blockIdx.x >> 3) * 64;    // row base
    const int nb   = (blockIdx.x & 7) * 64;     // col base
    const int mrow = rb + wv * 16 + l15;        // this lane's A row
    const int bf   = flag[0];

    f32x4 acc[4] = {};

    for (int k0 = 0; k0 < HIDDEN; k0 += 32) {
        const int kb = k0 + hi * 8;
        uint4 av = *(const uint4*)(pooled_bf + (size_t)mrow * (HIDDEN / 2) + (kb >> 1));
        bf16x8 afrag = __builtin_bit_cast(bf16x8, av);
#pragma unroll
        for (int j = 0; j < 4; ++j) {
            const int n = nb + j * 16 + l15;
            u16 bw[8];
            if (bf) {
                const u16* Wb = (const u16*)W;
#pragma unroll
                for (int i = 0; i < 8; ++i) bw[i] = Wb[(size_t)(kb + i) * HIDDEN + n];
            } else {
                const float* Wf = (const float*)W;
#pragma unroll
                for (int i = 0; i < 8; ++i) bw[i] = (u16)f2bf(Wf[(size_t)(kb + i) * HIDDEN + n]);
            }
            uint4 bv;
            bv.x = bw[0] | ((u32)bw[1] << 16);
            bv.y = bw[2] | ((u32)bw[3] << 16);
            bv.z = bw[4] | ((u32)bw[5] << 16);
            bv.w = bw[6] | ((u32)bw[7] << 16);
            bf16x8 bfrag = __builtin_bit_cast(bf16x8, bv);
            acc[j] = __builtin_amdgcn_mfma_f32_16x16x32_bf16(afrag, bfrag, acc[j], 0, 0, 0);
        }
    }

#pragma unroll
    for (int j = 0; j < 4; ++j) {
        const int n = nb + j * 16 + l15;
        const float bvn = bf ? bf2f(((const u16*)bias)[n]) : ((const float*)bias)[n];
#pragma unroll
        for (int r = 0; r < 4; ++r) {
            const int row = rb + wv * 16 + hi * 4 + r;
            h[(size_t)row * HIDDEN + n] = acc[j][r] + bvn;
        }
    }
}

// ---------------------------------------------------------------------------
// K3: per-column sum / sum-of-squares over the batch (BN batch stats).
__global__ __launch_bounds__(512) void k_stats(const float* __restrict__ h,
                                               float* __restrict__ sums,
                                               float* __restrict__ sumsq) {
    const int tid = threadIdx.x;
    const int r0 = blockIdx.x * 64;
    float s = 0.f, q = 0.f;
    for (int r = r0; r < r0 + 64; ++r) {
        float v = h[(size_t)r * HIDDEN + tid];
        s += v;
        q = fmaf(v, v, q);
    }
    atomicAdd(&sums[tid], s);
    atomicAdd(&sumsq[tid], q);
}

// ---------------------------------------------------------------------------
// K4: BN(batch stats) + ReLU + dot W_o + b_o -> logits; per-row BCE term.
__global__ __launch_bounds__(256) void k_out(const float* __restrict__ h,
                                             const float* __restrict__ sums,
                                             const float* __restrict__ sumsq,
                                             const void* __restrict__ gamma,
                                             const void* __restrict__ beta,
                                             const void* __restrict__ W_o,
                                             const void* __restrict__ b_o,
                                             const void* __restrict__ tvec,
                                             const int* __restrict__ flag,
                                             void* __restrict__ out,
                                             float* __restrict__ loss_acc) {
    const int lane = threadIdx.x & 63;
    const int wave = threadIdx.x >> 6;
    const int row  = blockIdx.x * 4 + wave;
    const float invN = 1.0f / (float)BATCH;
    const int bf = flag[0];
    const int c0 = lane * 8;

    float g[8], bt[8], wo[8];
    if (bf) {
        uint4 gu = *(const uint4*)((const u32*)gamma + lane * 4);
        uint4 bu = *(const uint4*)((const u32*)beta  + lane * 4);
        uint4 wu = *(const uint4*)((const u32*)W_o   + lane * 4);
        g[0]=bf2f(gu.x&0xffffu); g[1]=bf2f(gu.x>>16); g[2]=bf2f(gu.y&0xffffu); g[3]=bf2f(gu.y>>16);
        g[4]=bf2f(gu.z&0xffffu); g[5]=bf2f(gu.z>>16); g[6]=bf2f(gu.w&0xffffu); g[7]=bf2f(gu.w>>16);
        bt[0]=bf2f(bu.x&0xffffu); bt[1]=bf2f(bu.x>>16); bt[2]=bf2f(bu.y&0xffffu); bt[3]=bf2f(bu.y>>16);
        bt[4]=bf2f(bu.z&0xffffu); bt[5]=bf2f(bu.z>>16); bt[6]=bf2f(bu.w&0xffffu); bt[7]=bf2f(bu.w>>16);
        wo[0]=bf2f(wu.x&0xffffu); wo[1]=bf2f(wu.x>>16); wo[2]=bf2f(wu.y&0xffffu); wo[3]=bf2f(wu.y>>16);
        wo[4]=bf2f(wu.z&0xffffu); wo[5]=bf2f(wu.z>>16); wo[6]=bf2f(wu.w&0xffffu); wo[7]=bf2f(wu.w>>16);
    } else {
        float4 a, b2;
        a = *(const float4*)((const float*)gamma + c0); b2 = *(const float4*)((const float*)gamma + c0 + 4);
        g[0]=a.x; g[1]=a.y; g[2]=a.z; g[3]=a.w; g[4]=b2.x; g[5]=b2.y; g[6]=b2.z; g[7]=b2.w;
        a = *(const float4*)((const float*)beta + c0);  b2 = *(const float4*)((const float*)beta + c0 + 4);
        bt[0]=a.x; bt[1]=a.y; bt[2]=a.z; bt[3]=a.w; bt[4]=b2.x; bt[5]=b2.y; bt[6]=b2.z; bt[7]=b2.w;
        a = *(const float4*)((const float*)W_o + c0);   b2 = *(const float4*)((const float*)W_o + c0 + 4);
        wo[0]=a.x; wo[1]=a.y; wo[2]=a.z; wo[3]=a.w; wo[4]=b2.x; wo[5]=b2.y; wo[6]=b2.z; wo[7]=b2.w;
    }

    float hv[8], sm[8], sq[8];
    {
        const float* hp = h + (size_t)row * HIDDEN + c0;
        float4 a = *(const float4*)hp, b2 = *(const float4*)(hp + 4);
        hv[0]=a.x; hv[1]=a.y; hv[2]=a.z; hv[3]=a.w; hv[4]=b2.x; hv[5]=b2.y; hv[6]=b2.z; hv[7]=b2.w;
        a = *(const float4*)(sums + c0);  b2 = *(const float4*)(sums + c0 + 4);
        sm[0]=a.x; sm[1]=a.y; sm[2]=a.z; sm[3]=a.w; sm[4]=b2.x; sm[5]=b2.y; sm[6]=b2.z; sm[7]=b2.w;
        a = *(const float4*)(sumsq + c0); b2 = *(const float4*)(sumsq + c0 + 4);
        sq[0]=a.x; sq[1]=a.y; sq[2]=a.z; sq[3]=a.w; sq[4]=b2.x; sq[5]=b2.y; sq[6]=b2.z; sq[7]=b2.w;
    }

    float sum = 0.f;
#pragma unroll
    for (int k = 0; k < 8; ++k) {
        float mu  = sm[k] * invN;
        float var = sq[k] * invN - mu * mu;
        float xn  = (hv[k] - mu) * rsqrtf(var + BN_EPS);
        float y   = fmaf(g[k], xn, bt[k]);
        y = fmaxf(y, 0.f);
        sum = fmaf(y, wo[k], sum);
    }
#pragma unroll
    for (int o = 32; o > 0; o >>= 1) sum += __shfl_xor(sum, o);

    __shared__ float ls[4];
    if (lane == 0) {
        float bo = bf ? bf2f(((const u16*)b_o)[0]) : ((const float*)b_o)[0];
        float x = sum + bo;
        if (bf) ((u16*)out)[1 + row] = (u16)f2bf(x);
        else    ((float*)out)[1 + row] = x;
        float t = bf ? bf2f(((const u16*)tvec)[row]) : ((const float*)tvec)[row];
        float sp = fmaxf(x, 0.f) + log1pf(expf(-fabsf(x)));
        ls[wave] = sp - t * x;
    }
    __syncthreads();
    if (threadIdx.x == 0)
        atomicAdd(loss_acc, ls[0] + ls[1] + ls[2] + ls[3]);
}

// ---------------------------------------------------------------------------
// K5: finalize mean loss.
__global__ void k_fin(const float* __restrict__ loss_acc,
                      const int* __restrict__ flag, void* __restrict__ out) {
    if (threadIdx.x == 0) {
        float v = loss_acc[0] * (1.0f / (float)BATCH);
        if (flag[0]) ((u16*)out)[0] = (u16)f2bf(v);
        else         ((float*)out)[0] = v;
    }
}

// ---------------------------------------------------------------------------
extern "C" void kernel_launch(void* const* d_in, const int* in_sizes, int n_in,
                              void* d_out, int out_size, void* d_ws, size_t ws_size,
                              hipStream_t stream) {
    const int*  tokens = (const int*)d_in[0];
    const int*  seg    = (const int*)d_in[1];
    const void* tvec   = d_in[2];
    const void* emb    = d_in[3];
    const void* W_h    = d_in[4];
    const void* b_h    = d_in[5];
    const void* gamma  = d_in[6];
    const void* beta   = d_in[7];
    const void* W_o    = d_in[8];
    const void* b_o    = d_in[9];
    const int T = in_sizes[0];
    const int vocab = in_sizes[3] / HIDDEN;

    char* ws = (char*)d_ws;
    u32*   pooled_bf = (u32*)ws;                               // 4 MB (bf16-packed)
    float* h         = (float*)(ws + (size_t)8 * 1024 * 1024); // 8 MB
    float* sums      = (float*)(ws + (size_t)16 * 1024 * 1024);
    float* sumsq     = sums + HIDDEN;
    float* loss_acc  = sums + 2 * HIDDEN;
    int*   flag      = (int*)(loss_acc + 1);
    const size_t TABLE_OFF = (size_t)17 * 1024 * 1024;
    const size_t TABLE_BYTES = (size_t)vocab * HIDDEN * 2;
    u16* table = (u16*)(ws + TABLE_OFF);
    const int use_table = (ws_size >= TABLE_OFF + TABLE_BYTES) ? 1 : 0;

    (void)hipMemsetAsync(sums, 0, (2 * HIDDEN + 1) * sizeof(float), stream);

    k_detect<<<1, 64, 0, stream>>>((const u32*)emb, flag);
    if (use_table) {
        const int n4 = vocab * HIDDEN / 4;
        k_convert<<<2048, 256, 0, stream>>>((const f32x4*)emb, (uint2*)table, flag, n4);
    }
    k_pool  <<<BATCH,      256, 0, stream>>>(tokens, seg, emb, table, flag, use_table, pooled_bf, T);
    k_gemm  <<<(BATCH/64)*8, 256, 0, stream>>>(pooled_bf, W_h, b_h, flag, h);
    k_stats <<<BATCH / 64, 512, 0, stream>>>(h, sums, sumsq);
    k_out   <<<BATCH / 4,  256, 0, stream>>>(h, sums, sumsq, gamma, beta,
                                             W_o, b_o, tvec, flag, d_out, loss_acc);
    k_fin   <<<1, 64, 0, stream>>>(loss_acc, flag, d_out);
}